// Round 11
// baseline (50.369 us; speedup 1.0000x reference)
//
#include <hip/hip_runtime.h>
#include <math.h>

// TopKGate: logits = x @ W^T ; softmax ; top-2 ; scatter weights + indices(float).
// x: [8192,4096] f32, W: [64,4096] f32.
// d_out (f32 flat): weights [8192*64] then indices [8192*2] as floats.
//
// MFMA path: f32 as bf16 hi/lo split, 3 passes (hh+lh+hl; ll ~2^-16 dropped).
// Round-11: 3-waves/SIMD register class. 256-thr blocks, launch_bounds(256,3)
// (VGPR cap ~168), grid 1024 (k-split 2x blocks + 4x waves), B TRIPLE-buffer
// (3-phase slack ~830cyc vs L2) + x quad rotation (4-phase ~1100cyc vs HBM),
// 16 hand-unrolled phases with static buffer indices, SBAR-fenced.
// B stream is 512 MB L2 traffic (4x the x stream) - it needed the depth.
// Cross-block k-halves via 4 MB partial + validated wave-per-token finalize.

#define TOKENS 8192
#define DIM    4096
#define NEXP   64
#define NCHW   (DIM / 32)                    // 128 global k-chunks
#define FRAGS  ((size_t)NCHW * 4 * 64 * 8)   // 262144 shorts per array

#define BWAVES 4                             // waves per block (k-quarters of a half)
#define KB     2                             // k-split across blocks
#define KSEG   (DIM / KB / BWAVES)           // 512 k per wave
#define NCH    (KSEG / 32)                   // 16 chunks per wave

#define SBAR() __builtin_amdgcn_sched_barrier(0)

typedef __attribute__((ext_vector_type(8))) short  short8;
typedef __attribute__((ext_vector_type(4))) float  f32x4;
typedef __attribute__((ext_vector_type(8))) float  f32x8;

__device__ __forceinline__ void bf16split(float v, short& hi, short& lo) {
    unsigned u = __float_as_uint(v);
    hi = (short)(u >> 16);
    float r = v - __uint_as_float(u & 0xffff0000u);
    lo = (short)(__float_as_uint(r) >> 16);
}

// ---- prep: W[64][4096] -> fragment-ordered bf16 hi/lo ----
// Whf[((c*4+nt)*64+lane)*8 + j] = bf16hi(W[e][k]), e = nt*16+(lane&15),
// k = c*32 + (lane>>4)*8 + j.  (same k-map as A: consistency trick)
__global__ void tg_prepw(const float* __restrict__ W,
                         short* __restrict__ Whf, short* __restrict__ Wlf) {
    int gid  = blockIdx.x * 256 + threadIdx.x;   // 32768 threads
    int c    = gid >> 8, rem = gid & 255;
    int nt   = rem >> 6, lane = rem & 63;
    int e    = nt * 16 + (lane & 15);
    int kb   = c * 32 + (lane >> 4) * 8;
    const float* wp = W + (size_t)e * DIM + kb;
    short8 h, l;
#pragma unroll
    for (int j = 0; j < 8; ++j) {
        short hh, ll;
        bf16split(wp[j], hh, ll);
        h[j] = hh; l[j] = ll;
    }
    size_t o = ((size_t)(c * 4 + nt) * 64 + lane) * 8;
    *reinterpret_cast<short8*>(Whf + o) = h;
    *reinterpret_cast<short8*>(Wlf + o) = l;
}

// ---- main: GEMM (bf16-split MFMA), 16 tokens/block, k-eighth per wave ----
__global__ __launch_bounds__(256, 3)
void tg_mfma(const float* __restrict__ x,
             const short* __restrict__ Whf, const short* __restrict__ Wlf,
             float* __restrict__ part) {
    __shared__ float red[BWAVES * 16 * NEXP];    // 16 KB

    const int lane = threadIdx.x & 63;
    const int wave = threadIdx.x >> 6;           // k-quarter of this half
    const int tgp  = blockIdx.x >> 1;            // token group 0..511
    const int kb   = blockIdx.x & 1;             // k half
    const int t0   = tgp * 16;
    const int row  = lane & 15;                  // A row (token) / B,D col (expert)
    const int grp  = lane >> 4;
    const int c0   = kb * 64 + wave * NCH;       // global chunk base

    const float* xp = x + (size_t)(t0 + row) * DIM + c0 * 32 + grp * 8;

    f32x4 acc[4];
#pragma unroll
    for (int nt = 0; nt < 4; ++nt) acc[nt] = (f32x4){0.f, 0.f, 0.f, 0.f};

    short8 b0[8], b1[8], b2[8];
    auto loadB = [&](short8 (&b)[8], int c) {
        const size_t fo = (size_t)(c0 + c) * 2048 + (size_t)lane * 8;
        b[0] = *reinterpret_cast<const short8*>(Whf + fo);
        b[1] = *reinterpret_cast<const short8*>(Whf + fo + 512);
        b[2] = *reinterpret_cast<const short8*>(Whf + fo + 1024);
        b[3] = *reinterpret_cast<const short8*>(Whf + fo + 1536);
        b[4] = *reinterpret_cast<const short8*>(Wlf + fo);
        b[5] = *reinterpret_cast<const short8*>(Wlf + fo + 512);
        b[6] = *reinterpret_cast<const short8*>(Wlf + fo + 1024);
        b[7] = *reinterpret_cast<const short8*>(Wlf + fo + 1536);
    };
    auto ldx = [&](int c) {
        return *reinterpret_cast<const f32x8*>(xp + c * 32);
    };
    auto step = [&](const f32x8& xv, const short8 (&b)[8]) {
        short8 ah, al;
#pragma unroll
        for (int j = 0; j < 8; ++j) {
            short hh, ll;
            bf16split(xv[j], hh, ll);
            ah[j] = hh; al[j] = ll;
        }
        // 3-pass split: hh + lh + hl (ll ~ 2^-16 relative, dropped)
#pragma unroll
        for (int nt = 0; nt < 4; ++nt)
            acc[nt] = __builtin_amdgcn_mfma_f32_16x16x32_bf16(ah, b[nt], acc[nt], 0, 0, 0);
#pragma unroll
        for (int nt = 0; nt < 4; ++nt)
            acc[nt] = __builtin_amdgcn_mfma_f32_16x16x32_bf16(al, b[nt], acc[nt], 0, 0, 0);
#pragma unroll
        for (int nt = 0; nt < 4; ++nt)
            acc[nt] = __builtin_amdgcn_mfma_f32_16x16x32_bf16(ah, b[4 + nt], acc[nt], 0, 0, 0);
    };

    // prologue: B(0..2) and x(0..3) in flight
    loadB(b0, 0);
    loadB(b1, 1);
    loadB(b2, 2);
    f32x8 x0 = ldx(0);
    f32x8 x1 = ldx(1);
    f32x8 x2 = ldx(2);
    f32x8 x3 = ldx(3);
    SBAR();

    // 16 phases, fully unrolled; B at c%3 (3-phase depth), x at c%4 (4-phase)
#define PHASE(c, XB, BB)                                   \
    step(XB, BB);                                          \
    SBAR();                                                \
    if ((c) + 3 < NCH) loadB(BB, (c) + 3);                 \
    if ((c) + 4 < NCH) XB = ldx((c) + 4);                  \
    SBAR();

    PHASE(0,  x0, b0)
    PHASE(1,  x1, b1)
    PHASE(2,  x2, b2)
    PHASE(3,  x3, b0)
    PHASE(4,  x0, b1)
    PHASE(5,  x1, b2)
    PHASE(6,  x2, b0)
    PHASE(7,  x3, b1)
    PHASE(8,  x0, b2)
    PHASE(9,  x1, b0)
    PHASE(10, x2, b1)
    PHASE(11, x3, b2)
    PHASE(12, x0, b0)
    PHASE(13, x1, b1)
    PHASE(14, x2, b2)
    PHASE(15, x3, b0)
#undef PHASE

    // ---- dump partials to LDS (D layout m89: col=lane&15, row=grp*4+reg) ----
    float* my = red + wave * 16 * NEXP;
#pragma unroll
    for (int nt = 0; nt < 4; ++nt)
#pragma unroll
        for (int r = 0; r < 4; ++r)
            my[(grp * 4 + r) * NEXP + nt * 16 + row] = acc[nt][r];
    __syncthreads();

    // ---- deterministic fixed-order reduce + coalesced partial write ----
    const int tid = threadIdx.x;
    float* dst = part + ((size_t)kb * TOKENS + t0) * NEXP;
#pragma unroll
    for (int q = 0; q < 4; ++q) {
        const int idx = q * 256 + tid;
        float s = red[idx] + red[1024 + idx] + red[2048 + idx] + red[3072 + idx];
        dst[idx] = s;
    }
}

// ---- finalize: sum 2 k-halves, wave-per-token softmax + top-2 ----
__global__ __launch_bounds__(256)
void tg_final(const float* __restrict__ part,
              float* __restrict__ out_w, float* __restrict__ out_i) {
    const int lane = threadIdx.x & 63;
    const int wv   = threadIdx.x >> 6;
    const int t    = blockIdx.x * 4 + wv;        // one token per wave

    const float s = part[(size_t)t * NEXP + lane] +
                    part[((size_t)TOKENS + t) * NEXP + lane];

    // softmax over 64 lanes (butterfly: all lanes converge bit-identically)
    float m = s;
#pragma unroll
    for (int o = 32; o > 0; o >>= 1) m = fmaxf(m, __shfl_xor(m, o));
    float p = expf(s - m);
    float sum = p;
#pragma unroll
    for (int o = 32; o > 0; o >>= 1) sum += __shfl_xor(sum, o);
    const float prob = p / sum;

    // top-1: max value, tie -> lower index (jax top_k order)
    float v1 = prob; int i1 = lane;
#pragma unroll
    for (int o = 32; o > 0; o >>= 1) {
        float ov = __shfl_xor(v1, o); int oi = __shfl_xor(i1, o);
        if (ov > v1 || (ov == v1 && oi < i1)) { v1 = ov; i1 = oi; }
    }
    // top-2: mask winner (probs >= 0 > -1)
    float v2 = (lane == i1) ? -1.0f : prob; int i2 = lane;
#pragma unroll
    for (int o = 32; o > 0; o >>= 1) {
        float ov = __shfl_xor(v2, o); int oi = __shfl_xor(i2, o);
        if (ov > v2 || (ov == v2 && oi < i2)) { v2 = ov; i2 = oi; }
    }

    out_w[(size_t)t * NEXP + lane] = (lane == i1) ? v1 : (lane == i2) ? v2 : 0.0f;
    if (lane == 0) {
        out_i[(size_t)t * 2 + 0] = (float)i1;
        out_i[(size_t)t * 2 + 1] = (float)i2;
    }
}

extern "C" void kernel_launch(void* const* d_in, const int* in_sizes, int n_in,
                              void* d_out, int out_size, void* d_ws, size_t ws_size,
                              hipStream_t stream) {
    const float* x = (const float*)d_in[0];
    const float* W = (const float*)d_in[1];
    float* out_w = (float*)d_out;
    float* out_i = out_w + (size_t)TOKENS * NEXP;

    float* part = (float*)d_ws;                              // 2*8192*64*4 = 4 MB
    short* Whf  = (short*)((char*)d_ws + (size_t)KB * TOKENS * NEXP * 4);
    short* Wlf  = Whf + FRAGS;

    tg_prepw<<<dim3(128), dim3(256), 0, stream>>>(W, Whf, Wlf);
    tg_mfma <<<dim3(TOKENS / 16 * KB), dim3(256), 0, stream>>>(x, Whf, Wlf, part);
    tg_final<<<dim3(TOKENS / 4), dim3(256), 0, stream>>>(part, out_w, out_i);
}

// Round 13
// 43.787 us; speedup vs baseline: 1.1503x; 1.1503x over previous
//
#include <hip/hip_runtime.h>
#include <math.h>

// TopKGate: logits = x @ W^T ; softmax ; top-2 ; scatter weights + indices(float).
// x: [8192,4096] f32, W: [64,4096] f32.
// d_out (f32 flat): weights [8192*64] then indices [8192*2] as floats.
//
// MFMA path: f32 as bf16 hi/lo split, 3 passes (hh+lh+hl; ll ~2^-16 dropped).
// Round-13 (= round-12 with the vector-element reference compile fix):
// waves split TOKENS (8 waves x 16 tok = 128 tok/block) and share one B
// k-panel (K=512 = 128 KB) staged in LDS ONCE per block (one barrier total).
// Main loop: zero barriers; x is the ONLY vmem stream (register ring depth 6
// -> ~96 KB/CU in flight); B via ds_read_b128 ping-pong (lgkm-counted, off
// the vmcnt ledger). B global traffic 512->64 MB. Grid 512 = 64 tg x 8 ks.

#define TOKENS 8192
#define DIM    4096
#define NEXP   64
#define NCHW   (DIM / 32)                    // 128 global k-chunks
#define FRAGS  ((size_t)NCHW * 4 * 64 * 8)   // 262144 shorts per array

#define KS     8                             // k-split across blocks
#define KSEG   (DIM / KS)                    // 512 k per block
#define NCH    (KSEG / 32)                   // 16 chunks per block

#define SBAR() __builtin_amdgcn_sched_barrier(0)

typedef __attribute__((ext_vector_type(8))) short  short8;
typedef __attribute__((ext_vector_type(4))) float  f32x4;
typedef __attribute__((ext_vector_type(8))) float  f32x8;

__device__ __forceinline__ void bf16split(float v, short& hi, short& lo) {
    unsigned u = __float_as_uint(v);
    hi = (short)(u >> 16);
    float r = v - __uint_as_float(u & 0xffff0000u);
    lo = (short)(__float_as_uint(r) >> 16);
}

// ---- prep: W[64][4096] -> fragment-ordered bf16 hi/lo ----
// Whf[((c*4+nt)*64+lane)*8 + j] = bf16hi(W[e][k]), e = nt*16+(lane&15),
// k = c*32 + (lane>>4)*8 + j.  (same k-map as A: consistency trick)
__global__ void tg_prepw(const float* __restrict__ W,
                         short* __restrict__ Whf, short* __restrict__ Wlf) {
    int gid  = blockIdx.x * 256 + threadIdx.x;   // 32768 threads
    int c    = gid >> 8, rem = gid & 255;
    int nt   = rem >> 6, lane = rem & 63;
    int e    = nt * 16 + (lane & 15);
    int kb   = c * 32 + (lane >> 4) * 8;
    const float* wp = W + (size_t)e * DIM + kb;
    short8 h, l;
#pragma unroll
    for (int j = 0; j < 8; ++j) {
        short hh, ll;
        bf16split(wp[j], hh, ll);
        h[j] = hh; l[j] = ll;
    }
    size_t o = ((size_t)(c * 4 + nt) * 64 + lane) * 8;
    *reinterpret_cast<short8*>(Whf + o) = h;
    *reinterpret_cast<short8*>(Wlf + o) = l;
}

// ---- main: 128 tokens/block (8 waves x 16), shared B panel in LDS ----
__global__ __launch_bounds__(512, 2)
void tg_mfma(const float* __restrict__ x,
             const short* __restrict__ Whf, const short* __restrict__ Wlf,
             float* __restrict__ part) {
    // B panel: [hi/lo][chunk][nt*64+lane] short8 = 128 KB
    __shared__ short8 Bls[2][NCH][256];

    const int tid  = threadIdx.x;
    const int lane = tid & 63;
    const int wave = tid >> 6;                   // token sub-group 0..7
    const int tg   = blockIdx.x >> 3;            // token group 0..63
    const int ks   = blockIdx.x & 7;             // k split 0..7
    const int t0   = tg * 128 + wave * 16;
    const int row  = lane & 15;                  // A row (token) / D col tag
    const int grp  = lane >> 4;

    // ---- stage B panel: flat 2 x 64 KB copy, 16 x 16B per thread ----
    {
        const short8* srch = reinterpret_cast<const short8*>(Whf) + (size_t)ks * (NCH * 256);
        const short8* srcl = reinterpret_cast<const short8*>(Wlf) + (size_t)ks * (NCH * 256);
        short8* d0 = &Bls[0][0][0];
        short8* d1 = &Bls[1][0][0];
#pragma unroll
        for (int i = 0; i < 8; ++i) {
            d0[i * 512 + tid] = srch[i * 512 + tid];
            d1[i * 512 + tid] = srcl[i * 512 + tid];
        }
    }
    __syncthreads();   // the only barrier in the kernel

    const float* xp = x + (size_t)(t0 + row) * DIM + ks * KSEG + grp * 8;

    f32x4 acc[4];
#pragma unroll
    for (int nt = 0; nt < 4; ++nt) acc[nt] = (f32x4){0.f, 0.f, 0.f, 0.f};

    short8 bA[8], bB[8];
    auto dsB = [&](short8 (&b)[8], int c) {      // 8 x ds_read_b128, conflict-free
#pragma unroll
        for (int nt = 0; nt < 4; ++nt) {
            b[nt]     = Bls[0][c][nt * 64 + lane];
            b[4 + nt] = Bls[1][c][nt * 64 + lane];
        }
    };
    auto ldx = [&](int c) {
        return *reinterpret_cast<const f32x8*>(xp + c * 32);
    };
    auto cvt = [&](const f32x8& xv, short8& ah, short8& al) {
#pragma unroll
        for (int j = 0; j < 8; ++j) {
            short hh, ll;
            bf16split(xv[j], hh, ll);
            ah[j] = hh; al[j] = ll;
        }
    };
    auto mfma12 = [&](const short8& ah, const short8& al, const short8 (&b)[8]) {
        // 3-pass split: hh + lh + hl (ll ~ 2^-16 relative, dropped)
#pragma unroll
        for (int nt = 0; nt < 4; ++nt)
            acc[nt] = __builtin_amdgcn_mfma_f32_16x16x32_bf16(ah, b[nt], acc[nt], 0, 0, 0);
#pragma unroll
        for (int nt = 0; nt < 4; ++nt)
            acc[nt] = __builtin_amdgcn_mfma_f32_16x16x32_bf16(al, b[nt], acc[nt], 0, 0, 0);
#pragma unroll
        for (int nt = 0; nt < 4; ++nt)
            acc[nt] = __builtin_amdgcn_mfma_f32_16x16x32_bf16(ah, b[4 + nt], acc[nt], 0, 0, 0);
    };

    // prologue: B(0) from LDS, x ring depth 6 in flight
    f32x8 x0 = ldx(0), x1 = ldx(1), x2 = ldx(2),
          x3 = ldx(3), x4 = ldx(4), x5 = ldx(5);
    dsB(bA, 0);
    SBAR();

    short8 ah, al;
#define PH(c, XV, BC, BN)                                            \
    {                                                                \
        cvt(XV, ah, al);          /* convert frees XV's slot */      \
        SBAR();                                                      \
        if ((c) + 1 < NCH) dsB(BN, (c) + 1);                         \
        if ((c) + 6 < NCH) XV = ldx((c) + 6);                        \
        SBAR();                                                      \
        mfma12(ah, al, BC);                                          \
        SBAR();                                                      \
    }

    PH(0,  x0, bA, bB)
    PH(1,  x1, bB, bA)
    PH(2,  x2, bA, bB)
    PH(3,  x3, bB, bA)
    PH(4,  x4, bA, bB)
    PH(5,  x5, bB, bA)
    PH(6,  x0, bA, bB)
    PH(7,  x1, bB, bA)
    PH(8,  x2, bA, bB)
    PH(9,  x3, bB, bA)
    PH(10, x4, bA, bB)
    PH(11, x5, bB, bA)
    PH(12, x0, bA, bB)
    PH(13, x1, bB, bA)
    PH(14, x2, bA, bB)
    PH(15, x3, bB, bA)
#undef PH

    // ---- direct partial write: wave owns its 16 tokens, no reduction ----
    // D layout (m89-verified): col = lane&15, row = grp*4 + reg
    float* pp = part + ((size_t)ks * TOKENS + t0) * NEXP;
#pragma unroll
    for (int nt = 0; nt < 4; ++nt)
#pragma unroll
        for (int r = 0; r < 4; ++r)
            pp[(grp * 4 + r) * NEXP + nt * 16 + row] = acc[nt][r];
}

// ---- finalize: sum 8 k-split partials, wave-per-token softmax + top-2 ----
__global__ __launch_bounds__(256)
void tg_final(const float* __restrict__ part,
              float* __restrict__ out_w, float* __restrict__ out_i) {
    const int lane = threadIdx.x & 63;
    const int wv   = threadIdx.x >> 6;
    const int t    = blockIdx.x * 4 + wv;        // one token per wave

    float s = 0.0f;
#pragma unroll
    for (int k = 0; k < KS; ++k)                 // coalesced 256-B reads
        s += part[((size_t)k * TOKENS + t) * NEXP + lane];

    // softmax over 64 lanes (butterfly: all lanes converge bit-identically)
    float m = s;
#pragma unroll
    for (int o = 32; o > 0; o >>= 1) m = fmaxf(m, __shfl_xor(m, o));
    float p = expf(s - m);
    float sum = p;
#pragma unroll
    for (int o = 32; o > 0; o >>= 1) sum += __shfl_xor(sum, o);
    const float prob = p / sum;

    // top-1: max value, tie -> lower index (jax top_k order)
    float v1 = prob; int i1 = lane;
#pragma unroll
    for (int o = 32; o > 0; o >>= 1) {
        float ov = __shfl_xor(v1, o); int oi = __shfl_xor(i1, o);
        if (ov > v1 || (ov == v1 && oi < i1)) { v1 = ov; i1 = oi; }
    }
    // top-2: mask winner (probs >= 0 > -1)
    float v2 = (lane == i1) ? -1.0f : prob; int i2 = lane;
#pragma unroll
    for (int o = 32; o > 0; o >>= 1) {
        float ov = __shfl_xor(v2, o); int oi = __shfl_xor(i2, o);
        if (ov > v2 || (ov == v2 && oi < i2)) { v2 = ov; i2 = oi; }
    }

    out_w[(size_t)t * NEXP + lane] = (lane == i1) ? v1 : (lane == i2) ? v2 : 0.0f;
    if (lane == 0) {
        out_i[(size_t)t * 2 + 0] = (float)i1;
        out_i[(size_t)t * 2 + 1] = (float)i2;
    }
}

extern "C" void kernel_launch(void* const* d_in, const int* in_sizes, int n_in,
                              void* d_out, int out_size, void* d_ws, size_t ws_size,
                              hipStream_t stream) {
    const float* x = (const float*)d_in[0];
    const float* W = (const float*)d_in[1];
    float* out_w = (float*)d_out;
    float* out_i = out_w + (size_t)TOKENS * NEXP;

    float* part = (float*)d_ws;                              // 8*8192*64*4 = 16 MB
    short* Whf  = (short*)((char*)d_ws + (size_t)KS * TOKENS * NEXP * 4);
    short* Wlf  = Whf + FRAGS;

    tg_prepw<<<dim3(128), dim3(256), 0, stream>>>(W, Whf, Wlf);
    tg_mfma <<<dim3(64 * KS), dim3(512), 0, stream>>>(x, Whf, Wlf, part);
    tg_final<<<dim3(TOKENS / 4), dim3(256), 0, stream>>>(part, out_w, out_i);
}